// Round 2
// baseline (1530.869 us; speedup 1.0000x reference)
//
#include <hip/hip_runtime.h>

#define N_CHR 50000
#define E_CHR 500000
#define N_SLV 30000
#define E_SLV 300000
#define BATCH_B 256
#define FEAT 64
#define DIM 128
#define HALF 64
#define ENSN 3

// ---------------- CSR build ----------------

__global__ void hist_k(const int* __restrict__ dst, int* __restrict__ cnt, int E) {
    int i = blockIdx.x * blockDim.x + threadIdx.x;
    int stride = gridDim.x * blockDim.x;
    for (; i < E; i += stride) atomicAdd(&cnt[dst[i]], 1);
}

// single-block exclusive scan (shuffle-based), writes off[0..n] (off[n]=total)
__global__ void scan_fast_k(const int* __restrict__ cnt, int* __restrict__ off, int n) {
    const int T = 1024;
    int tid = threadIdx.x;
    int chunk = (n + T - 1) / T;
    int s = tid * chunk;
    int e = s + chunk;
    if (s > n) s = n;
    if (e > n) e = n;
    int sum = 0;
    for (int i = s; i < e; i++) sum += cnt[i];
    // inclusive wave scan of per-thread sums
    int lane = tid & 63, wave = tid >> 6;
    int v = sum;
#pragma unroll
    for (int ofs = 1; ofs < 64; ofs <<= 1) {
        int t = __shfl_up(v, ofs, 64);
        if (lane >= ofs) v += t;
    }
    __shared__ int wsum[16];
    if (lane == 63) wsum[wave] = v;
    __syncthreads();
    if (tid == 0) {
        int c = 0;
        for (int w2 = 0; w2 < 16; w2++) { int t = wsum[w2]; wsum[w2] = c; c += t; }
    }
    __syncthreads();
    int prefix = wsum[wave] + (v - sum);   // exclusive prefix over all threads
    int run = prefix;
    for (int i = s; i < e; i++) { off[i] = run; run += cnt[i]; }
    if (e == n) off[n] = run;              // all qualifying threads write the same total
}

__global__ void fill_k(const int* __restrict__ src, const int* __restrict__ dst,
                       int E, int* __restrict__ cursor, int* __restrict__ csr) {
    int i = blockIdx.x * blockDim.x + threadIdx.x;
    int stride = gridDim.x * blockDim.x;
    for (; i < E; i += stride) {
        int p = atomicAdd(&cursor[dst[i]], 1);
        csr[p] = src[i];
    }
}

// per-graph node ranges from the SORTED batch vector: start[b] = lower_bound(batch, b)
__global__ void bounds_k(const int* __restrict__ batch, int n, int* __restrict__ start) {
    int b = blockIdx.x * blockDim.x + threadIdx.x;
    if (b > BATCH_B) return;
    if (b == BATCH_B) { start[b] = n; return; }
    int lo = 0, hi = n;
    while (lo < hi) {
        int mid = (lo + hi) >> 1;
        if (batch[mid] < b) lo = mid + 1; else hi = mid;
    }
    start[b] = lo;
}

// ---------------- pull aggregation: Y[i,:] = sum_{j in in(i)} H[csr[j],:] ----------------

template<int F, bool RELU>
__global__ void agg_k(const float* __restrict__ H, const int* __restrict__ off,
                      const int* __restrict__ csr, float* __restrict__ Y) {
    int i = blockIdx.x;
    int f = threadIdx.x;               // F threads
    int s = off[i], e2 = off[i + 1];
    float acc = 0.f;
    int j = s;
    for (; j + 1 < e2; j += 2) {       // unroll-2: two gathers in flight
        int s0 = csr[j], s1 = csr[j + 1];
        acc += H[s0 * F + f];
        acc += H[s1 * F + f];
    }
    if (j < e2) acc += H[csr[j] * F + f];
    Y[i * F + f] = RELU ? fmaxf(acc, 0.f) : acc;
}

// ---------------- node-row GEMM: Y[n, 0:COLS] = X[n, 0:K] @ W[K, COLS] ----------------

template<int K, int COLS, int TM, bool RELU>
__global__ void gemm_k(const float* __restrict__ X, const float* __restrict__ W,
                       float* __restrict__ Y, int n) {
    __shared__ float xs[TM][K];
    int base = blockIdx.x * TM;
    int c = threadIdx.x;               // COLS threads
    for (int i = c; i < TM * K; i += COLS) {
        int m = i / K, k = i - m * K;
        int node = base + m;
        xs[m][k] = (node < n) ? X[node * K + k] : 0.f;
    }
    __syncthreads();
    float acc[TM];
#pragma unroll
    for (int m = 0; m < TM; m++) acc[m] = 0.f;
    for (int k = 0; k < K; k++) {
        float w = W[k * COLS + c];     // coalesced; W tile stays hot in L1/L2
#pragma unroll
        for (int m = 0; m < TM; m++) acc[m] = fmaf(xs[m][k], w, acc[m]);  // xs broadcast
    }
#pragma unroll
    for (int m = 0; m < TM; m++) {
        int node = base + m;
        if (node < n) {
            float v = acc[m];
            Y[node * COLS + c] = RELU ? fmaxf(v, 0.f) : v;
        }
    }
}

// ---------------- global_add_pool: segmented sum over sorted batch ranges ----------------

__global__ void pool_seg_k(const float* __restrict__ H, const int* __restrict__ start,
                           float* __restrict__ rep, int colOff) {
    int b = blockIdx.x;
    int f = threadIdx.x;               // HALF=64 threads
    int s = start[b], e = start[b + 1];
    float acc = 0.f;
    for (int i = s; i < e; i++) acc += H[i * HALF + f];
    rep[b * (2 * ENSN * HALF) + colOff + f] = acc;
}

// ---------------- projection heads -> hg[B, 2*ENS*DIM] ----------------

__global__ void head_k(const float* __restrict__ rep,
                       const float* __restrict__ cW, const float* __restrict__ cB,
                       const float* __restrict__ sW, const float* __restrict__ sB,
                       float* __restrict__ hg) {
    int b = blockIdx.x;
    int be = blockIdx.y;               // 0..2 chr ens, 3..5 slv ens
    int branch = be / ENSN, e = be % ENSN;
    int c = threadIdx.x;               // DIM=128 threads
    __shared__ float r[HALF];
    const float* repRow = rep + b * (2 * ENSN * HALF) + branch * (ENSN * HALF) + e * HALF;
    if (c < HALF) r[c] = repRow[c];
    __syncthreads();
    const float* W = (branch ? sW : cW) + e * HALF * DIM;
    const float* Bv = (branch ? sB : cB) + e * DIM;
    float acc = Bv[c];
#pragma unroll
    for (int k = 0; k < HALF; k++) acc = fmaf(r[k], W[k * DIM + c], acc);
    hg[b * (2 * ENSN * DIM) + branch * (ENSN * DIM) + e * DIM + c] = fmaxf(acc, 0.f);
}

// ---------------- final MLP: out[b] = (relu(hg@fc1+b1)) @ fc2 + b2 ----------------

__global__ void final_k(const float* __restrict__ hg, const float* __restrict__ W1,
                        const float* __restrict__ b1, const float* __restrict__ W2,
                        const float* __restrict__ b2, float* __restrict__ out) {
    int b = blockIdx.x;
    int c = threadIdx.x;               // 128 threads
    const int IN = 2 * ENSN * DIM;     // 768
    __shared__ float row[2 * ENSN * DIM];
    for (int i = c; i < IN; i += DIM) row[i] = hg[b * IN + i];
    __syncthreads();
    float acc = b1[c];
    for (int k = 0; k < IN; k++) acc = fmaf(row[k], W1[k * DIM + c], acc);
    acc = fmaxf(acc, 0.f);
    __shared__ float red[DIM];
    red[c] = acc * W2[c];
    __syncthreads();
    for (int s = DIM / 2; s > 0; s >>= 1) {
        if (c < s) red[c] += red[c + s];
        __syncthreads();
    }
    if (c == 0) out[b] = red[0] + b2[0];
}

// ---------------- host ----------------

extern "C" void kernel_launch(void* const* d_in, const int* in_sizes, int n_in,
                              void* d_out, int out_size, void* d_ws, size_t ws_size,
                              hipStream_t stream) {
    const float* chr_x = (const float*)d_in[0];
    const float* slv_x = (const float*)d_in[1];
    const int* chr_ei = (const int*)d_in[2];   // [2, E_CHR]: row0 src, row1 dst
    const int* slv_ei = (const int*)d_in[3];
    const int* chr_batch = (const int*)d_in[4];
    const int* slv_batch = (const int*)d_in[5];
    const float* chr_W0 = (const float*)d_in[6];
    const float* chr_W1 = (const float*)d_in[7];
    const float* chr_W2 = (const float*)d_in[8];
    const float* slv_W0 = (const float*)d_in[9];
    const float* slv_W1 = (const float*)d_in[10];
    const float* slv_W2 = (const float*)d_in[11];
    const float* cfc_W = (const float*)d_in[12];
    const float* cfc_b = (const float*)d_in[13];
    const float* sfc_W = (const float*)d_in[14];
    const float* sfc_b = (const float*)d_in[15];
    const float* fc1_W = (const float*)d_in[16];
    const float* fc1_b = (const float*)d_in[17];
    const float* fc2_W = (const float*)d_in[18];
    const float* fc2_b = (const float*)d_in[19];
    float* out = (float*)d_out;

    // workspace carve-up (256B aligned)
    char* w = (char*)d_ws;
    auto carve = [&](size_t bytes) {
        void* p = (void*)w;
        w += (bytes + 255) & ~(size_t)255;
        return p;
    };
    int* off_chr = (int*)carve((N_CHR + 1) * sizeof(int));
    int* csr_chr = (int*)carve((size_t)E_CHR * sizeof(int));
    int* off_slv = (int*)carve((N_SLV + 1) * sizeof(int));
    int* csr_slv = (int*)carve((size_t)E_SLV * sizeof(int));
    int* cursor  = (int*)carve((size_t)N_CHR * sizeof(int));
    int* start_chr = (int*)carve((BATCH_B + 1) * sizeof(int));
    int* start_slv = (int*)carve((BATCH_B + 1) * sizeof(int));
    float* aggX  = (float*)carve((size_t)N_CHR * FEAT * sizeof(float));
    float* bufA  = (float*)carve((size_t)N_CHR * DIM * sizeof(float));
    float* bufB  = (float*)carve((size_t)N_CHR * DIM * sizeof(float));
    float* rep   = (float*)carve((size_t)BATCH_B * 2 * ENSN * HALF * sizeof(float));
    float* hg    = (float*)carve((size_t)BATCH_B * 2 * ENSN * DIM * sizeof(float));

    // ---- CSR build (chr) ----
    hipMemsetAsync(cursor, 0, N_CHR * sizeof(int), stream);
    hist_k<<<512, 256, 0, stream>>>(chr_ei + E_CHR, cursor, E_CHR);
    scan_fast_k<<<1, 1024, 0, stream>>>(cursor, off_chr, N_CHR);
    hipMemcpyAsync(cursor, off_chr, N_CHR * sizeof(int), hipMemcpyDeviceToDevice, stream);
    fill_k<<<512, 256, 0, stream>>>(chr_ei, chr_ei + E_CHR, E_CHR, cursor, csr_chr);

    // ---- CSR build (slv) ----
    hipMemsetAsync(cursor, 0, N_SLV * sizeof(int), stream);
    hist_k<<<512, 256, 0, stream>>>(slv_ei + E_SLV, cursor, E_SLV);
    scan_fast_k<<<1, 1024, 0, stream>>>(cursor, off_slv, N_SLV);
    hipMemcpyAsync(cursor, off_slv, N_SLV * sizeof(int), hipMemcpyDeviceToDevice, stream);
    fill_k<<<512, 256, 0, stream>>>(slv_ei, slv_ei + E_SLV, E_SLV, cursor, csr_slv);

    // ---- pool segment bounds (batch vectors are sorted) ----
    bounds_k<<<1, 320, 0, stream>>>(chr_batch, N_CHR, start_chr);
    bounds_k<<<1, 320, 0, stream>>>(slv_batch, N_SLV, start_slv);

    // ---- chr branch ----
    // layer-1 rewrite: agg(x) once (shared across ensembles), then GEMM per ens
    agg_k<FEAT, false><<<N_CHR, FEAT, 0, stream>>>(chr_x, off_chr, csr_chr, aggX);
    for (int e = 0; e < ENSN; e++) {
        gemm_k<FEAT, DIM, 16, true><<<(N_CHR + 15) / 16, DIM, 0, stream>>>(
            aggX, chr_W0 + (size_t)e * FEAT * DIM, bufA, N_CHR);                 // h1 = relu(aggX@W0)
        agg_k<DIM, false><<<N_CHR, DIM, 0, stream>>>(bufA, off_chr, csr_chr, bufB);  // a1 = agg(h1)
        gemm_k<DIM, DIM, 16, true><<<(N_CHR + 15) / 16, DIM, 0, stream>>>(
            bufB, chr_W1 + (size_t)e * DIM * DIM, bufA, N_CHR);                  // h2 = relu(a1@W1)
        gemm_k<DIM, HALF, 16, false><<<(N_CHR + 15) / 16, HALF, 0, stream>>>(
            bufA, chr_W2 + (size_t)e * DIM * HALF, bufB, N_CHR);                 // p3 = h2@W2
        agg_k<HALF, true><<<N_CHR, HALF, 0, stream>>>(bufB, off_chr, csr_chr, bufA); // h3 = relu(agg(p3))
        pool_seg_k<<<BATCH_B, HALF, 0, stream>>>(bufA, start_chr, rep, e * HALF);
    }

    // ---- slv branch ----
    agg_k<FEAT, false><<<N_SLV, FEAT, 0, stream>>>(slv_x, off_slv, csr_slv, aggX);
    for (int e = 0; e < ENSN; e++) {
        gemm_k<FEAT, DIM, 16, true><<<(N_SLV + 15) / 16, DIM, 0, stream>>>(
            aggX, slv_W0 + (size_t)e * FEAT * DIM, bufA, N_SLV);
        agg_k<DIM, false><<<N_SLV, DIM, 0, stream>>>(bufA, off_slv, csr_slv, bufB);
        gemm_k<DIM, DIM, 16, true><<<(N_SLV + 15) / 16, DIM, 0, stream>>>(
            bufB, slv_W1 + (size_t)e * DIM * DIM, bufA, N_SLV);
        gemm_k<DIM, HALF, 16, false><<<(N_SLV + 15) / 16, HALF, 0, stream>>>(
            bufA, slv_W2 + (size_t)e * DIM * HALF, bufB, N_SLV);
        agg_k<HALF, true><<<N_SLV, HALF, 0, stream>>>(bufB, off_slv, csr_slv, bufA);
        pool_seg_k<<<BATCH_B, HALF, 0, stream>>>(bufA, start_slv, rep, ENSN * HALF + e * HALF);
    }

    // ---- heads + final MLP ----
    head_k<<<dim3(BATCH_B, 2 * ENSN), DIM, 0, stream>>>(rep, cfc_W, cfc_b, sfc_W, sfc_b, hg);
    final_k<<<BATCH_B, DIM, 0, stream>>>(hg, fc1_W, fc1_b, fc2_W, fc2_b, out);
}

// Round 3
// 727.776 us; speedup vs baseline: 2.1035x; 2.1035x over previous
//
#include <hip/hip_runtime.h>

#define N_CHR 50000
#define E_CHR 500000
#define N_SLV 30000
#define E_SLV 300000
#define BATCH_B 256
#define FEAT 64
#define DIM 128
#define HALF 64
#define ENSN 3
#define SCAN_BLOCKS 256

typedef unsigned int u32;
typedef unsigned short u16;
typedef __attribute__((ext_vector_type(8))) short short8;
typedef __attribute__((ext_vector_type(4))) float floatx4;

// ---------------- bf16 helpers (manual, round-to-nearest-even) ----------------

__device__ inline u16 f2b(float f) {
    u32 u = __builtin_bit_cast(u32, f);
    u += 0x7FFFu + ((u >> 16) & 1u);
    return (u16)(u >> 16);
}
__device__ inline float b2f(u16 h) {
    u32 u = (u32)h << 16;
    return __builtin_bit_cast(float, u);
}
__device__ inline float b2f_lo(u32 v) { return __builtin_bit_cast(float, v << 16); }
__device__ inline float b2f_hi(u32 v) { return __builtin_bit_cast(float, v & 0xFFFF0000u); }
__device__ inline u32 packb(float a, float b) { return (u32)f2b(a) | ((u32)f2b(b) << 16); }

// ---------------- CSR build ----------------

__global__ void hist_k(const int* __restrict__ dst, int* __restrict__ cnt, int E) {
    int i = blockIdx.x * blockDim.x + threadIdx.x;
    int stride = gridDim.x * blockDim.x;
    for (; i < E; i += stride) atomicAdd(&cnt[dst[i]], 1);
}

// 256-thread block exclusive scan helper
__device__ inline int block_exscan(int v) {
    int lane = threadIdx.x & 63, wv = threadIdx.x >> 6;
    int inc = v;
#pragma unroll
    for (int o = 1; o < 64; o <<= 1) {
        int t = __shfl_up(inc, o, 64);
        if (lane >= o) inc += t;
    }
    __shared__ int ws[4];
    if (lane == 63) ws[wv] = inc;
    __syncthreads();
    if (threadIdx.x == 0) {
        int c = 0;
#pragma unroll
        for (int k = 0; k < 4; k++) { int t = ws[k]; ws[k] = c; c += t; }
    }
    __syncthreads();
    return ws[wv] + inc - v;
}

// phase A: per-block sums (chunk = ceil(n/SCAN_BLOCKS) <= 256, one elem/thread)
__global__ void scanA_k(const int* __restrict__ cnt, int* __restrict__ bsum, int n) {
    int b = blockIdx.x, t = threadIdx.x;
    int chunk = (n + SCAN_BLOCKS - 1) / SCAN_BLOCKS;
    int s = b * chunk + t;
    int v = (t < chunk && s < n) ? cnt[s] : 0;
    // block reduce
    int lane = t & 63, wv = t >> 6;
#pragma unroll
    for (int o = 32; o > 0; o >>= 1) v += __shfl_down(v, o, 64);
    __shared__ int ws[4];
    if (lane == 0) ws[wv] = v;
    __syncthreads();
    if (t == 0) bsum[b] = ws[0] + ws[1] + ws[2] + ws[3];
}

// phase B: exclusive-scan bsum[SCAN_BLOCKS] in place; thread 255 writes off[n]=total
__global__ void scanB_k(int* __restrict__ bsum, int* __restrict__ off, int n) {
    int t = threadIdx.x;
    int v = bsum[t];
    int p = block_exscan(v);
    bsum[t] = p;
    if (t == SCAN_BLOCKS - 1) off[n] = p + v;
}

// phase C: write off[i] and cursor[i]
__global__ void scanC_k(const int* __restrict__ cnt, const int* __restrict__ bsum,
                        int* __restrict__ off, int* __restrict__ cursor, int n) {
    int b = blockIdx.x, t = threadIdx.x;
    int chunk = (n + SCAN_BLOCKS - 1) / SCAN_BLOCKS;
    int s = b * chunk + t;
    int v = (t < chunk && s < n) ? cnt[s] : 0;
    int p = block_exscan(v);
    if (t < chunk && s < n) {
        int o = bsum[b] + p;
        off[s] = o;
        cursor[s] = o;
    }
}

__global__ void fill_k(const int* __restrict__ src, const int* __restrict__ dst,
                       int E, int* __restrict__ cursor, int* __restrict__ csr) {
    int i = blockIdx.x * blockDim.x + threadIdx.x;
    int stride = gridDim.x * blockDim.x;
    for (; i < E; i += stride) {
        int p = atomicAdd(&cursor[dst[i]], 1);
        csr[p] = src[i];
    }
}

// per-graph node ranges from the SORTED batch vector
__global__ void bounds_k(const int* __restrict__ batch, int n, int* __restrict__ start) {
    int b = blockIdx.x * blockDim.x + threadIdx.x;
    if (b > BATCH_B) return;
    if (b == BATCH_B) { start[b] = n; return; }
    int lo = 0, hi = n;
    while (lo < hi) {
        int mid = (lo + hi) >> 1;
        if (batch[mid] < b) lo = mid + 1; else hi = mid;
    }
    start[b] = lo;
}

// ---------------- weight convert+transpose: W[E][K][N] f32 -> Wt[E][N][K] bf16 ----------------

__global__ void wconv_k(const float* __restrict__ W, u16* __restrict__ Wt, int K, int N) {
    int e = blockIdx.y;
    int idx = blockIdx.x * 256 + threadIdx.x;
    if (idx >= K * N) return;
    int k = idx / N, nn = idx - k * N;
    Wt[((size_t)e * N + nn) * K + k] = f2b(W[(size_t)e * K * N + idx]);
}

// ---------------- layer-1 aggregation: fp32 in, bf16 out (shared across ens) ----------------

__global__ void agg1_k(const float* __restrict__ H, const int* __restrict__ off,
                       const int* __restrict__ csr, u16* __restrict__ Y) {
    int i = blockIdx.x;
    int f = threadIdx.x;               // 64 threads
    int s = off[i], e2 = off[i + 1];
    float acc = 0.f;
    int j = s;
    for (; j + 1 < e2; j += 2) {
        int s0 = csr[j], s1 = csr[j + 1];
        acc += H[s0 * FEAT + f] + H[s1 * FEAT + f];
    }
    if (j < e2) acc += H[csr[j] * FEAT + f];
    Y[(size_t)i * FEAT + f] = f2b(acc);
}

// ---------------- bf16 aggregation, F=128, ens-batched: Y[e][i] = (relu?)sum H[e][csr[j]] ----------------

template<bool RELU>
__global__ void aggb128_k(const u16* __restrict__ H, const int* __restrict__ off,
                          const int* __restrict__ csr, u16* __restrict__ Y, int n) {
    int e = blockIdx.y;
    const u32* He = (const u32*)(H + (size_t)e * n * DIM);
    u32* Ye = (u32*)(Y + (size_t)e * n * DIM);
    int i = blockIdx.x;
    int f = threadIdx.x;               // 64 threads, 2 feats each
    int s = off[i], e2 = off[i + 1];
    float a0 = 0.f, a1 = 0.f;
    int j = s;
    for (; j + 3 < e2; j += 4) {
        int s0 = csr[j], s1 = csr[j + 1], s2 = csr[j + 2], s3 = csr[j + 3];
        u32 v0 = He[(size_t)s0 * 64 + f], v1 = He[(size_t)s1 * 64 + f];
        u32 v2 = He[(size_t)s2 * 64 + f], v3 = He[(size_t)s3 * 64 + f];
        a0 += b2f_lo(v0) + b2f_lo(v1) + b2f_lo(v2) + b2f_lo(v3);
        a1 += b2f_hi(v0) + b2f_hi(v1) + b2f_hi(v2) + b2f_hi(v3);
    }
    for (; j < e2; j++) {
        u32 v = He[(size_t)csr[j] * 64 + f];
        a0 += b2f_lo(v); a1 += b2f_hi(v);
    }
    if (RELU) { a0 = fmaxf(a0, 0.f); a1 = fmaxf(a1, 0.f); }
    Ye[(size_t)i * 64 + f] = packb(a0, a1);
}

// ---------------- bf16 aggregation, F=64, ens-batched, 2 nodes/block ----------------

template<bool RELU>
__global__ void aggb64_k(const u16* __restrict__ H, const int* __restrict__ off,
                         const int* __restrict__ csr, u16* __restrict__ Y, int n) {
    int e = blockIdx.y;
    const u32* He = (const u32*)(H + (size_t)e * n * HALF);
    u32* Ye = (u32*)(Y + (size_t)e * n * HALF);
    int i = blockIdx.x * 2 + (threadIdx.x >> 5);
    if (i >= n) return;
    int f = threadIdx.x & 31;          // 32 feats-pairs per node
    int s = off[i], e2 = off[i + 1];
    float a0 = 0.f, a1 = 0.f;
    int j = s;
    for (; j + 1 < e2; j += 2) {
        u32 v0 = He[(size_t)csr[j] * 32 + f], v1 = He[(size_t)csr[j + 1] * 32 + f];
        a0 += b2f_lo(v0) + b2f_lo(v1);
        a1 += b2f_hi(v0) + b2f_hi(v1);
    }
    if (j < e2) {
        u32 v = He[(size_t)csr[j] * 32 + f];
        a0 += b2f_lo(v); a1 += b2f_hi(v);
    }
    if (RELU) { a0 = fmaxf(a0, 0.f); a1 = fmaxf(a1, 0.f); }
    Ye[(size_t)i * 32 + f] = packb(a0, a1);
}

// ---------------- MFMA GEMM: Y[e][n][COLS] = (relu?)(X[e?][n][K] @ Wt[e][COLS][K]^T) ----------------
// 256 threads = 4 waves, 16 rows/wave, wave loops over n-tiles and K.
// Layouts (verified m89/m91): A[m=lane&15][k=quad*8+j]; B from Wt rows same pattern;
// C/D: col=lane&15, row=quad*4+reg.

template<int K, int COLS, bool RELU>
__global__ __launch_bounds__(256) void gemm_mfma_k(
        const u16* __restrict__ X, size_t xEnsStride,
        const u16* __restrict__ Wt, u16* __restrict__ Y, int n) {
    const int e = blockIdx.y;
    const u16* Xe = X + (size_t)e * xEnsStride;
    const u16* We = Wt + (size_t)e * COLS * K;
    u16* Ye = Y + (size_t)e * (size_t)n * COLS;
    int wave = threadIdx.x >> 6;
    int lane = threadIdx.x & 63;
    int m0 = blockIdx.x * 64 + wave * 16;
    if (m0 >= n) return;
    int quad = lane >> 4;
    int mrow = m0 + (lane & 15);
    int mclamp = mrow < n ? mrow : n - 1;
    int nq = lane & 15;
    constexpr int NT = COLS / 16;
    constexpr int KT = K / 32;
    floatx4 acc[NT];
#pragma unroll
    for (int t = 0; t < NT; t++) acc[t] = (floatx4)(0.f);
#pragma unroll
    for (int kt = 0; kt < KT; kt++) {
        int k0 = kt * 32 + quad * 8;
        short8 a = *(const short8*)(Xe + (size_t)mclamp * K + k0);
#pragma unroll
        for (int t = 0; t < NT; t++) {
            short8 b = *(const short8*)(We + (size_t)(t * 16 + nq) * K + k0);
            acc[t] = __builtin_amdgcn_mfma_f32_16x16x32_bf16(a, b, acc[t], 0, 0, 0);
        }
    }
    int rbase = quad * 4;
#pragma unroll
    for (int t = 0; t < NT; t++) {
#pragma unroll
        for (int r = 0; r < 4; r++) {
            int row = m0 + rbase + r;
            if (row < n) {
                float v = acc[t][r];
                if (RELU) v = fmaxf(v, 0.f);
                Ye[(size_t)row * COLS + t * 16 + nq] = f2b(v);
            }
        }
    }
}

// ---------------- global_add_pool (bf16 in, fp32 out), ens-batched ----------------

__global__ void pool_b_k(const u16* __restrict__ H, const int* __restrict__ start,
                         float* __restrict__ rep, int n, int colOff) {
    int b = blockIdx.x, e = blockIdx.y, f = threadIdx.x;   // 64 threads
    const u16* He = H + (size_t)e * n * HALF;
    int s = start[b], e2 = start[b + 1];
    float acc = 0.f;
    for (int i = s; i < e2; i++) acc += b2f(He[(size_t)i * HALF + f]);
    rep[b * (2 * ENSN * HALF) + colOff + e * HALF + f] = acc;
}

// ---------------- projection heads -> hg[B, 2*ENS*DIM] (fp32) ----------------

__global__ void head_k(const float* __restrict__ rep,
                       const float* __restrict__ cW, const float* __restrict__ cB,
                       const float* __restrict__ sW, const float* __restrict__ sB,
                       float* __restrict__ hg) {
    int b = blockIdx.x;
    int be = blockIdx.y;
    int branch = be / ENSN, e = be % ENSN;
    int c = threadIdx.x;               // 128 threads
    __shared__ float r[HALF];
    const float* repRow = rep + b * (2 * ENSN * HALF) + branch * (ENSN * HALF) + e * HALF;
    if (c < HALF) r[c] = repRow[c];
    __syncthreads();
    const float* W = (branch ? sW : cW) + e * HALF * DIM;
    const float* Bv = (branch ? sB : cB) + e * DIM;
    float acc = Bv[c];
#pragma unroll
    for (int k = 0; k < HALF; k++) acc = fmaf(r[k], W[k * DIM + c], acc);
    hg[b * (2 * ENSN * DIM) + branch * (ENSN * DIM) + e * DIM + c] = fmaxf(acc, 0.f);
}

// ---------------- final MLP ----------------

__global__ void final_k(const float* __restrict__ hg, const float* __restrict__ W1,
                        const float* __restrict__ b1, const float* __restrict__ W2,
                        const float* __restrict__ b2, float* __restrict__ out) {
    int b = blockIdx.x;
    int c = threadIdx.x;               // 128 threads
    const int IN = 2 * ENSN * DIM;     // 768
    __shared__ float row[2 * ENSN * DIM];
    for (int i = c; i < IN; i += DIM) row[i] = hg[b * IN + i];
    __syncthreads();
    float acc = b1[c];
    for (int k = 0; k < IN; k++) acc = fmaf(row[k], W1[k * DIM + c], acc);
    acc = fmaxf(acc, 0.f);
    __shared__ float red[DIM];
    red[c] = acc * W2[c];
    __syncthreads();
    for (int s = DIM / 2; s > 0; s >>= 1) {
        if (c < s) red[c] += red[c + s];
        __syncthreads();
    }
    if (c == 0) out[b] = red[0] + b2[0];
}

// ---------------- host ----------------

extern "C" void kernel_launch(void* const* d_in, const int* in_sizes, int n_in,
                              void* d_out, int out_size, void* d_ws, size_t ws_size,
                              hipStream_t stream) {
    const float* chr_x = (const float*)d_in[0];
    const float* slv_x = (const float*)d_in[1];
    const int* chr_ei = (const int*)d_in[2];
    const int* slv_ei = (const int*)d_in[3];
    const int* chr_batch = (const int*)d_in[4];
    const int* slv_batch = (const int*)d_in[5];
    const float* chr_W0 = (const float*)d_in[6];
    const float* chr_W1 = (const float*)d_in[7];
    const float* chr_W2 = (const float*)d_in[8];
    const float* slv_W0 = (const float*)d_in[9];
    const float* slv_W1 = (const float*)d_in[10];
    const float* slv_W2 = (const float*)d_in[11];
    const float* cfc_W = (const float*)d_in[12];
    const float* cfc_b = (const float*)d_in[13];
    const float* sfc_W = (const float*)d_in[14];
    const float* sfc_b = (const float*)d_in[15];
    const float* fc1_W = (const float*)d_in[16];
    const float* fc1_b = (const float*)d_in[17];
    const float* fc2_W = (const float*)d_in[18];
    const float* fc2_b = (const float*)d_in[19];
    float* out = (float*)d_out;

    char* w = (char*)d_ws;
    auto carve = [&](size_t bytes) {
        void* p = (void*)w;
        w += (bytes + 255) & ~(size_t)255;
        return p;
    };
    int* off_chr = (int*)carve((N_CHR + 1) * sizeof(int));
    int* csr_chr = (int*)carve((size_t)E_CHR * sizeof(int));
    int* off_slv = (int*)carve((N_SLV + 1) * sizeof(int));
    int* csr_slv = (int*)carve((size_t)E_SLV * sizeof(int));
    int* cnt     = (int*)carve((size_t)N_CHR * sizeof(int));
    int* cursor  = (int*)carve((size_t)N_CHR * sizeof(int));
    int* bsum    = (int*)carve(SCAN_BLOCKS * sizeof(int));
    int* start_chr = (int*)carve((BATCH_B + 1) * sizeof(int));
    int* start_slv = (int*)carve((BATCH_B + 1) * sizeof(int));
    // bf16 transposed weights
    u16* cW0t = (u16*)carve((size_t)ENSN * DIM * FEAT * sizeof(u16));
    u16* cW1t = (u16*)carve((size_t)ENSN * DIM * DIM * sizeof(u16));
    u16* cW2t = (u16*)carve((size_t)ENSN * HALF * DIM * sizeof(u16));
    u16* sW0t = (u16*)carve((size_t)ENSN * DIM * FEAT * sizeof(u16));
    u16* sW1t = (u16*)carve((size_t)ENSN * DIM * DIM * sizeof(u16));
    u16* sW2t = (u16*)carve((size_t)ENSN * HALF * DIM * sizeof(u16));
    // activations (bf16)
    u16* aggX = (u16*)carve((size_t)N_CHR * FEAT * sizeof(u16));
    u16* bufP = (u16*)carve((size_t)ENSN * N_CHR * DIM * sizeof(u16));
    u16* bufQ = (u16*)carve((size_t)ENSN * N_CHR * DIM * sizeof(u16));
    float* rep = (float*)carve((size_t)BATCH_B * 2 * ENSN * HALF * sizeof(float));
    float* hg  = (float*)carve((size_t)BATCH_B * 2 * ENSN * DIM * sizeof(float));

    // ---- weight convert+transpose (bf16) ----
    wconv_k<<<dim3((FEAT * DIM + 255) / 256, ENSN), 256, 0, stream>>>(chr_W0, cW0t, FEAT, DIM);
    wconv_k<<<dim3((DIM * DIM + 255) / 256, ENSN), 256, 0, stream>>>(chr_W1, cW1t, DIM, DIM);
    wconv_k<<<dim3((DIM * HALF + 255) / 256, ENSN), 256, 0, stream>>>(chr_W2, cW2t, DIM, HALF);
    wconv_k<<<dim3((FEAT * DIM + 255) / 256, ENSN), 256, 0, stream>>>(slv_W0, sW0t, FEAT, DIM);
    wconv_k<<<dim3((DIM * DIM + 255) / 256, ENSN), 256, 0, stream>>>(slv_W1, sW1t, DIM, DIM);
    wconv_k<<<dim3((DIM * HALF + 255) / 256, ENSN), 256, 0, stream>>>(slv_W2, sW2t, DIM, HALF);

    // ---- CSR build (chr) ----
    hipMemsetAsync(cnt, 0, N_CHR * sizeof(int), stream);
    hist_k<<<512, 256, 0, stream>>>(chr_ei + E_CHR, cnt, E_CHR);
    scanA_k<<<SCAN_BLOCKS, 256, 0, stream>>>(cnt, bsum, N_CHR);
    scanB_k<<<1, SCAN_BLOCKS, 0, stream>>>(bsum, off_chr, N_CHR);
    scanC_k<<<SCAN_BLOCKS, 256, 0, stream>>>(cnt, bsum, off_chr, cursor, N_CHR);
    fill_k<<<512, 256, 0, stream>>>(chr_ei, chr_ei + E_CHR, E_CHR, cursor, csr_chr);

    // ---- CSR build (slv) ----
    hipMemsetAsync(cnt, 0, N_SLV * sizeof(int), stream);
    hist_k<<<512, 256, 0, stream>>>(slv_ei + E_SLV, cnt, E_SLV);
    scanA_k<<<SCAN_BLOCKS, 256, 0, stream>>>(cnt, bsum, N_SLV);
    scanB_k<<<1, SCAN_BLOCKS, 0, stream>>>(bsum, off_slv, N_SLV);
    scanC_k<<<SCAN_BLOCKS, 256, 0, stream>>>(cnt, bsum, off_slv, cursor, N_SLV);
    fill_k<<<512, 256, 0, stream>>>(slv_ei, slv_ei + E_SLV, E_SLV, cursor, csr_slv);

    // ---- pool segment bounds ----
    bounds_k<<<1, 320, 0, stream>>>(chr_batch, N_CHR, start_chr);
    bounds_k<<<1, 320, 0, stream>>>(slv_batch, N_SLV, start_slv);

    // ---- chr branch (ens-batched via gridDim.y) ----
    agg1_k<<<N_CHR, FEAT, 0, stream>>>(chr_x, off_chr, csr_chr, aggX);
    gemm_mfma_k<FEAT, DIM, true><<<dim3((N_CHR + 63) / 64, ENSN), 256, 0, stream>>>(
        aggX, 0, cW0t, bufP, N_CHR);                                     // h1
    aggb128_k<false><<<dim3(N_CHR, ENSN), 64, 0, stream>>>(bufP, off_chr, csr_chr, bufQ, N_CHR);
    gemm_mfma_k<DIM, DIM, true><<<dim3((N_CHR + 63) / 64, ENSN), 256, 0, stream>>>(
        bufQ, (size_t)N_CHR * DIM, cW1t, bufP, N_CHR);                   // h2
    gemm_mfma_k<DIM, HALF, false><<<dim3((N_CHR + 63) / 64, ENSN), 256, 0, stream>>>(
        bufP, (size_t)N_CHR * DIM, cW2t, bufQ, N_CHR);                   // p3
    aggb64_k<true><<<dim3((N_CHR + 1) / 2, ENSN), 64, 0, stream>>>(bufQ, off_chr, csr_chr, bufP, N_CHR);
    pool_b_k<<<dim3(BATCH_B, ENSN), HALF, 0, stream>>>(bufP, start_chr, rep, N_CHR, 0);

    // ---- slv branch ----
    agg1_k<<<N_SLV, FEAT, 0, stream>>>(slv_x, off_slv, csr_slv, aggX);
    gemm_mfma_k<FEAT, DIM, true><<<dim3((N_SLV + 63) / 64, ENSN), 256, 0, stream>>>(
        aggX, 0, sW0t, bufP, N_SLV);
    aggb128_k<false><<<dim3(N_SLV, ENSN), 64, 0, stream>>>(bufP, off_slv, csr_slv, bufQ, N_SLV);
    gemm_mfma_k<DIM, DIM, true><<<dim3((N_SLV + 63) / 64, ENSN), 256, 0, stream>>>(
        bufQ, (size_t)N_SLV * DIM, sW1t, bufP, N_SLV);
    gemm_mfma_k<DIM, HALF, false><<<dim3((N_SLV + 63) / 64, ENSN), 256, 0, stream>>>(
        bufP, (size_t)N_SLV * DIM, sW2t, bufQ, N_SLV);
    aggb64_k<true><<<dim3((N_SLV + 1) / 2, ENSN), 64, 0, stream>>>(bufQ, off_slv, csr_slv, bufP, N_SLV);
    pool_b_k<<<dim3(BATCH_B, ENSN), HALF, 0, stream>>>(bufP, start_slv, rep, N_SLV, ENSN * HALF);

    // ---- heads + final MLP ----
    head_k<<<dim3(BATCH_B, 2 * ENSN), DIM, 0, stream>>>(rep, cfc_W, cfc_b, sfc_W, sfc_b, hg);
    final_k<<<BATCH_B, DIM, 0, stream>>>(hg, fc1_W, fc1_b, fc2_W, fc2_b, out);
}

// Round 4
// 534.076 us; speedup vs baseline: 2.8664x; 1.3627x over previous
//
#include <hip/hip_runtime.h>

#define N_CHR 50000
#define E_CHR 500000
#define N_SLV 30000
#define E_SLV 300000
#define BATCH_B 256
#define FEAT 64
#define DIM 128
#define HALF 64
#define ENSN 3
#define SCAN_BLOCKS 256

typedef unsigned int u32;
typedef unsigned short u16;
typedef __attribute__((ext_vector_type(8))) short short8;
typedef __attribute__((ext_vector_type(4))) float floatx4;
typedef __attribute__((ext_vector_type(2))) unsigned int u32x2;

// ---------------- bf16 helpers (round-to-nearest-even) ----------------

__device__ inline u16 f2b(float f) {
    u32 u = __builtin_bit_cast(u32, f);
    u += 0x7FFFu + ((u >> 16) & 1u);
    return (u16)(u >> 16);
}
__device__ inline float b2f_lo(u32 v) { return __builtin_bit_cast(float, v << 16); }
__device__ inline float b2f_hi(u32 v) { return __builtin_bit_cast(float, v & 0xFFFF0000u); }
__device__ inline u32 packb(float a, float b) { return (u32)f2b(a) | ((u32)f2b(b) << 16); }

// ---------------- input convert: fp32 -> bf16, both branches in one launch ----------------

__global__ void xconv_k(const float* __restrict__ xc, const float* __restrict__ xs,
                        u16* __restrict__ oc, u16* __restrict__ os) {
    const int nc = N_CHR * FEAT, ns = N_SLV * FEAT;
    int i = blockIdx.x * blockDim.x + threadIdx.x;
    int stride = gridDim.x * blockDim.x;
    for (; i < nc + ns; i += stride) {
        if (i < nc) oc[i] = f2b(xc[i]);
        else os[i - nc] = f2b(xs[i - nc]);
    }
}

// ---------------- weight convert+transpose: W[E][K][N] f32 -> Wt[E][N][K] bf16 ----------------
// grid.z = 0: chr, 1: slv

__global__ void wconv_k(const float* __restrict__ Wc, const float* __restrict__ Ws,
                        u16* __restrict__ Wtc, u16* __restrict__ Wts, int K, int N) {
    const float* W = blockIdx.z ? Ws : Wc;
    u16* Wt = blockIdx.z ? Wts : Wtc;
    int e = blockIdx.y;
    int idx = blockIdx.x * 256 + threadIdx.x;
    if (idx >= K * N) return;
    int k = idx / N, nn = idx - k * N;
    Wt[((size_t)e * N + nn) * K + k] = f2b(W[(size_t)e * K * N + idx]);
}

// ---------------- CSR build (both graphs per launch) ----------------

__global__ void hist_both_k(const int* __restrict__ cdst, const int* __restrict__ sdst,
                            int* __restrict__ cnt) {
    int i = blockIdx.x * blockDim.x + threadIdx.x;
    int stride = gridDim.x * blockDim.x;
    for (; i < E_CHR + E_SLV; i += stride) {
        if (i < E_CHR) atomicAdd(&cnt[cdst[i]], 1);
        else atomicAdd(&cnt[N_CHR + sdst[i - E_CHR]], 1);
    }
}

__device__ inline int block_exscan(int v) {
    int lane = threadIdx.x & 63, wv = threadIdx.x >> 6;
    int inc = v;
#pragma unroll
    for (int o = 1; o < 64; o <<= 1) {
        int t = __shfl_up(inc, o, 64);
        if (lane >= o) inc += t;
    }
    __shared__ int ws[4];
    if (lane == 63) ws[wv] = inc;
    __syncthreads();
    if (threadIdx.x == 0) {
        int c = 0;
#pragma unroll
        for (int k = 0; k < 4; k++) { int t = ws[k]; ws[k] = c; c += t; }
    }
    __syncthreads();
    int r = ws[wv] + inc - v;
    __syncthreads();
    return r;
}

// phase A: per-block sums; blocks 0..255 chr, 256..511 slv
__global__ void scanA_k(const int* __restrict__ cnt, int* __restrict__ bsum) {
    int b = blockIdx.x, t = threadIdx.x;
    int isS = b >= SCAN_BLOCKS;
    int n = isS ? N_SLV : N_CHR;
    const int* c = cnt + (isS ? N_CHR : 0);
    int bb = b & (SCAN_BLOCKS - 1);
    int chunk = (n + SCAN_BLOCKS - 1) / SCAN_BLOCKS;
    int s = bb * chunk + t;
    int v = (t < chunk && s < n) ? c[s] : 0;
    int lane = t & 63, wv = t >> 6;
#pragma unroll
    for (int o = 32; o > 0; o >>= 1) v += __shfl_down(v, o, 64);
    __shared__ int ws[4];
    if (lane == 0) ws[wv] = v;
    __syncthreads();
    if (t == 0) bsum[b] = ws[0] + ws[1] + ws[2] + ws[3];
}

// phase B: exclusive-scan both bsum halves; write totals
__global__ void scanB_k(int* __restrict__ bsum, int* __restrict__ off_c, int* __restrict__ off_s) {
    int t = threadIdx.x;
    int v = bsum[t];
    int p = block_exscan(v);
    bsum[t] = p;
    if (t == SCAN_BLOCKS - 1) off_c[N_CHR] = p + v;
    int v2 = bsum[SCAN_BLOCKS + t];
    int p2 = block_exscan(v2);
    bsum[SCAN_BLOCKS + t] = p2;
    if (t == SCAN_BLOCKS - 1) off_s[N_SLV] = p2 + v2;
}

// phase C: write off[i] and cursor[i] for both graphs
__global__ void scanC_k(const int* __restrict__ cnt, const int* __restrict__ bsum,
                        int* __restrict__ off_c, int* __restrict__ off_s,
                        int* __restrict__ cursor) {
    int b = blockIdx.x, t = threadIdx.x;
    int isS = b >= SCAN_BLOCKS;
    int n = isS ? N_SLV : N_CHR;
    const int* c = cnt + (isS ? N_CHR : 0);
    int* off = isS ? off_s : off_c;
    int* cur = cursor + (isS ? N_CHR : 0);
    int bb = b & (SCAN_BLOCKS - 1);
    int chunk = (n + SCAN_BLOCKS - 1) / SCAN_BLOCKS;
    int s = bb * chunk + t;
    int v = (t < chunk && s < n) ? c[s] : 0;
    int p = block_exscan(v);
    if (t < chunk && s < n) {
        int o = bsum[b] + p;
        off[s] = o;
        cur[s] = o;
    }
}

__global__ void fill_both_k(const int* __restrict__ cei, const int* __restrict__ sei,
                            int* __restrict__ cursor,
                            int* __restrict__ csr_c, int* __restrict__ csr_s) {
    int i = blockIdx.x * blockDim.x + threadIdx.x;
    int stride = gridDim.x * blockDim.x;
    for (; i < E_CHR + E_SLV; i += stride) {
        if (i < E_CHR) {
            int p = atomicAdd(&cursor[cei[E_CHR + i]], 1);
            csr_c[p] = cei[i];
        } else {
            int j = i - E_CHR;
            int p = atomicAdd(&cursor[N_CHR + sei[E_SLV + j]], 1);
            csr_s[p] = sei[j];
        }
    }
}

// per-graph node ranges from SORTED batch vectors (both in one block)
__global__ void bounds_both_k(const int* __restrict__ cb, const int* __restrict__ sb,
                              int* __restrict__ start_c, int* __restrict__ start_s) {
    int t = threadIdx.x + blockIdx.x * blockDim.x;
    int isS = t >= 320;
    int b = isS ? t - 320 : t;
    if (b > BATCH_B) return;
    const int* batch = isS ? sb : cb;
    int n = isS ? N_SLV : N_CHR;
    int* start = isS ? start_s : start_c;
    if (b == BATCH_B) { start[b] = n; return; }
    int lo = 0, hi = n;
    while (lo < hi) {
        int mid = (lo + hi) >> 1;
        if (batch[mid] < b) lo = mid + 1; else hi = mid;
    }
    start[b] = lo;
}

// ---------------- layer-1 aggregation: bf16 in/out, 2 nodes/block ----------------

__global__ void agg1_k(const u16* __restrict__ X, const int* __restrict__ off,
                       const int* __restrict__ csr, u16* __restrict__ Y, int n) {
    int i = blockIdx.x * 2 + (threadIdx.x >> 5);
    if (i >= n) return;
    int fp = threadIdx.x & 31;           // feat-pair (FEAT=64 -> 32 u32)
    const u32* X32 = (const u32*)X;
    int s = off[i], e2 = off[i + 1];
    float a0 = 0.f, a1 = 0.f;
    int j = s;
    for (; j + 3 < e2; j += 4) {
        u32 v0 = X32[(size_t)csr[j] * 32 + fp];
        u32 v1 = X32[(size_t)csr[j + 1] * 32 + fp];
        u32 v2 = X32[(size_t)csr[j + 2] * 32 + fp];
        u32 v3 = X32[(size_t)csr[j + 3] * 32 + fp];
        a0 += b2f_lo(v0) + b2f_lo(v1) + b2f_lo(v2) + b2f_lo(v3);
        a1 += b2f_hi(v0) + b2f_hi(v1) + b2f_hi(v2) + b2f_hi(v3);
    }
    for (; j < e2; j++) {
        u32 v = X32[(size_t)csr[j] * 32 + fp];
        a0 += b2f_lo(v); a1 += b2f_hi(v);
    }
    ((u32*)Y)[(size_t)i * 32 + fp] = packb(a0, a1);
}

// ---------------- bf16 aggregation, F=128, ens-batched, 2 nodes/block, 8B loads ----------------

template<bool RELU>
__global__ void aggb128_k(const u16* __restrict__ H, const int* __restrict__ off,
                          const int* __restrict__ csr, u16* __restrict__ Y, int n) {
    int e = blockIdx.y;
    const u32* He = (const u32*)(H + (size_t)e * n * DIM);   // 64 u32 per row
    u32* Ye = (u32*)(Y + (size_t)e * n * DIM);
    int i = blockIdx.x * 2 + (threadIdx.x >> 5);
    if (i >= n) return;
    int fp = threadIdx.x & 31;           // covers u32 pair fp*2, fp*2+1
    int s = off[i], e2 = off[i + 1];
    float a0 = 0.f, a1 = 0.f, a2 = 0.f, a3 = 0.f;
    int j = s;
    for (; j + 3 < e2; j += 4) {
        u32x2 v0 = *(const u32x2*)(He + (size_t)csr[j] * 64 + fp * 2);
        u32x2 v1 = *(const u32x2*)(He + (size_t)csr[j + 1] * 64 + fp * 2);
        u32x2 v2 = *(const u32x2*)(He + (size_t)csr[j + 2] * 64 + fp * 2);
        u32x2 v3 = *(const u32x2*)(He + (size_t)csr[j + 3] * 64 + fp * 2);
        a0 += b2f_lo(v0.x) + b2f_lo(v1.x) + b2f_lo(v2.x) + b2f_lo(v3.x);
        a1 += b2f_hi(v0.x) + b2f_hi(v1.x) + b2f_hi(v2.x) + b2f_hi(v3.x);
        a2 += b2f_lo(v0.y) + b2f_lo(v1.y) + b2f_lo(v2.y) + b2f_lo(v3.y);
        a3 += b2f_hi(v0.y) + b2f_hi(v1.y) + b2f_hi(v2.y) + b2f_hi(v3.y);
    }
    for (; j < e2; j++) {
        u32x2 v = *(const u32x2*)(He + (size_t)csr[j] * 64 + fp * 2);
        a0 += b2f_lo(v.x); a1 += b2f_hi(v.x);
        a2 += b2f_lo(v.y); a3 += b2f_hi(v.y);
    }
    if (RELU) {
        a0 = fmaxf(a0, 0.f); a1 = fmaxf(a1, 0.f);
        a2 = fmaxf(a2, 0.f); a3 = fmaxf(a3, 0.f);
    }
    u32x2 o; o.x = packb(a0, a1); o.y = packb(a2, a3);
    *(u32x2*)(Ye + (size_t)i * 64 + fp * 2) = o;
}

// ---------------- bf16 aggregation, F=64, ens-batched, 4 nodes/block, 8B loads ----------------

template<bool RELU>
__global__ void aggb64_k(const u16* __restrict__ H, const int* __restrict__ off,
                         const int* __restrict__ csr, u16* __restrict__ Y, int n) {
    int e = blockIdx.y;
    const u32* He = (const u32*)(H + (size_t)e * n * HALF);  // 32 u32 per row
    u32* Ye = (u32*)(Y + (size_t)e * n * HALF);
    int i = blockIdx.x * 4 + (threadIdx.x >> 4);
    if (i >= n) return;
    int fp = threadIdx.x & 15;           // covers u32 pair fp*2, fp*2+1
    int s = off[i], e2 = off[i + 1];
    float a0 = 0.f, a1 = 0.f, a2 = 0.f, a3 = 0.f;
    int j = s;
    for (; j + 3 < e2; j += 4) {
        u32x2 v0 = *(const u32x2*)(He + (size_t)csr[j] * 32 + fp * 2);
        u32x2 v1 = *(const u32x2*)(He + (size_t)csr[j + 1] * 32 + fp * 2);
        u32x2 v2 = *(const u32x2*)(He + (size_t)csr[j + 2] * 32 + fp * 2);
        u32x2 v3 = *(const u32x2*)(He + (size_t)csr[j + 3] * 32 + fp * 2);
        a0 += b2f_lo(v0.x) + b2f_lo(v1.x) + b2f_lo(v2.x) + b2f_lo(v3.x);
        a1 += b2f_hi(v0.x) + b2f_hi(v1.x) + b2f_hi(v2.x) + b2f_hi(v3.x);
        a2 += b2f_lo(v0.y) + b2f_lo(v1.y) + b2f_lo(v2.y) + b2f_lo(v3.y);
        a3 += b2f_hi(v0.y) + b2f_hi(v1.y) + b2f_hi(v2.y) + b2f_hi(v3.y);
    }
    for (; j < e2; j++) {
        u32x2 v = *(const u32x2*)(He + (size_t)csr[j] * 32 + fp * 2);
        a0 += b2f_lo(v.x); a1 += b2f_hi(v.x);
        a2 += b2f_lo(v.y); a3 += b2f_hi(v.y);
    }
    if (RELU) {
        a0 = fmaxf(a0, 0.f); a1 = fmaxf(a1, 0.f);
        a2 = fmaxf(a2, 0.f); a3 = fmaxf(a3, 0.f);
    }
    u32x2 o; o.x = packb(a0, a1); o.y = packb(a2, a3);
    *(u32x2*)(Ye + (size_t)i * 32 + fp * 2) = o;
}

// ---------------- MFMA GEMM, LDS-staged weights, 64 rows/wave, 256 rows/block ----------------
// A[m=lane&15][k=quad*8+j]; B from Wt rows, same lane mapping; C/D col=lane&15,row=quad*4+reg.

#define WPAD 8

template<int K, int COLS, bool RELU>
__global__ __launch_bounds__(256) void gemm_mfma_k(
        const u16* __restrict__ X, size_t xEnsStride,
        const u16* __restrict__ Wt, u16* __restrict__ Y, int n) {
    __shared__ u16 wlds[COLS * (K + WPAD)];
    const int e = blockIdx.y;
    const u16* Xe = X + (size_t)e * xEnsStride;
    const u16* We = Wt + (size_t)e * COLS * K;
    u16* Ye = Y + (size_t)e * (size_t)n * COLS;
    // cooperative W stage (16B chunks, padded rows)
    for (int c = threadIdx.x; c < COLS * (K / 8); c += 256) {
        int row = c / (K / 8), seg = c - row * (K / 8);
        *(short8*)(wlds + row * (K + WPAD) + seg * 8) = *(const short8*)(We + (size_t)row * K + seg * 8);
    }
    __syncthreads();
    int wave = threadIdx.x >> 6, lane = threadIdx.x & 63;
    int quad = lane >> 4, nq = lane & 15;
    int m0 = blockIdx.x * 256 + wave * 64;
    if (m0 >= n) return;
    constexpr int NT = COLS / 16, KT = K / 32;
    floatx4 acc[4][NT];
#pragma unroll
    for (int rg = 0; rg < 4; rg++)
#pragma unroll
        for (int t = 0; t < NT; t++) acc[rg][t] = (floatx4)(0.f);
#pragma unroll
    for (int kt = 0; kt < KT; kt++) {
        int k0 = kt * 32 + quad * 8;
        short8 a[4];
#pragma unroll
        for (int rg = 0; rg < 4; rg++) {
            int row = m0 + rg * 16 + nq;
            int rc = row < n ? row : n - 1;
            a[rg] = *(const short8*)(Xe + (size_t)rc * K + k0);
        }
#pragma unroll
        for (int t = 0; t < NT; t++) {
            short8 b = *(const short8*)(wlds + (t * 16 + nq) * (K + WPAD) + k0);
#pragma unroll
            for (int rg = 0; rg < 4; rg++)
                acc[rg][t] = __builtin_amdgcn_mfma_f32_16x16x32_bf16(a[rg], b, acc[rg][t], 0, 0, 0);
        }
    }
    int rbase = quad * 4;
#pragma unroll
    for (int rg = 0; rg < 4; rg++)
#pragma unroll
        for (int t = 0; t < NT; t++)
#pragma unroll
            for (int r = 0; r < 4; r++) {
                int row = m0 + rg * 16 + rbase + r;
                if (row < n) {
                    float v = acc[rg][t][r];
                    if (RELU) v = fmaxf(v, 0.f);
                    Ye[(size_t)row * COLS + t * 16 + nq] = f2b(v);
                }
            }
}

// ---------------- global_add_pool: 4 waves/block, u32 loads, LDS combine ----------------

__global__ __launch_bounds__(256) void pool_b_k(const u16* __restrict__ H,
                                                const int* __restrict__ start,
                                                float* __restrict__ rep, int n, int colOff) {
    int b = blockIdx.x, e = blockIdx.y;
    const u32* He = (const u32*)(H + (size_t)e * n * HALF);
    int t = threadIdx.x;
    int wave = t >> 6, lane = t & 63;
    int fp = lane & 31, rp = lane >> 5;          // feat-pair, row-parity
    int s = start[b], e2 = start[b + 1];
    float a0 = 0.f, a1 = 0.f;
    for (int i = s + wave * 2 + rp; i < e2; i += 8) {
        u32 v = He[(size_t)i * 32 + fp];
        a0 += b2f_lo(v); a1 += b2f_hi(v);
    }
    __shared__ float sm[8][32][2];
    sm[wave * 2 + rp][fp][0] = a0;
    sm[wave * 2 + rp][fp][1] = a1;
    __syncthreads();
    if (t < 64) {
        int f2 = t & 31, half = t >> 5;
        float acc = 0.f;
#pragma unroll
        for (int k = 0; k < 8; k++) acc += sm[k][f2][half];
        rep[b * (2 * ENSN * HALF) + colOff + e * HALF + f2 * 2 + half] = acc;
    }
}

// ---------------- projection heads -> hg[B, 2*ENS*DIM] (fp32) ----------------

__global__ void head_k(const float* __restrict__ rep,
                       const float* __restrict__ cW, const float* __restrict__ cB,
                       const float* __restrict__ sW, const float* __restrict__ sB,
                       float* __restrict__ hg) {
    int b = blockIdx.x;
    int be = blockIdx.y;
    int branch = be / ENSN, e = be % ENSN;
    int c = threadIdx.x;               // 128 threads
    __shared__ float r[HALF];
    const float* repRow = rep + b * (2 * ENSN * HALF) + branch * (ENSN * HALF) + e * HALF;
    if (c < HALF) r[c] = repRow[c];
    __syncthreads();
    const float* W = (branch ? sW : cW) + e * HALF * DIM;
    const float* Bv = (branch ? sB : cB) + e * DIM;
    float acc = Bv[c];
#pragma unroll
    for (int k = 0; k < HALF; k++) acc = fmaf(r[k], W[k * DIM + c], acc);
    hg[b * (2 * ENSN * DIM) + branch * (ENSN * DIM) + e * DIM + c] = fmaxf(acc, 0.f);
}

// ---------------- final MLP ----------------

__global__ void final_k(const float* __restrict__ hg, const float* __restrict__ W1,
                        const float* __restrict__ b1, const float* __restrict__ W2,
                        const float* __restrict__ b2, float* __restrict__ out) {
    int b = blockIdx.x;
    int c = threadIdx.x;               // 128 threads
    const int IN = 2 * ENSN * DIM;     // 768
    __shared__ float row[2 * ENSN * DIM];
    for (int i = c; i < IN; i += DIM) row[i] = hg[b * IN + i];
    __syncthreads();
    float acc = b1[c];
    for (int k = 0; k < IN; k++) acc = fmaf(row[k], W1[k * DIM + c], acc);
    acc = fmaxf(acc, 0.f);
    __shared__ float red[DIM];
    red[c] = acc * W2[c];
    __syncthreads();
    for (int s = DIM / 2; s > 0; s >>= 1) {
        if (c < s) red[c] += red[c + s];
        __syncthreads();
    }
    if (c == 0) out[b] = red[0] + b2[0];
}

// ---------------- host ----------------

extern "C" void kernel_launch(void* const* d_in, const int* in_sizes, int n_in,
                              void* d_out, int out_size, void* d_ws, size_t ws_size,
                              hipStream_t stream) {
    const float* chr_x = (const float*)d_in[0];
    const float* slv_x = (const float*)d_in[1];
    const int* chr_ei = (const int*)d_in[2];
    const int* slv_ei = (const int*)d_in[3];
    const int* chr_batch = (const int*)d_in[4];
    const int* slv_batch = (const int*)d_in[5];
    const float* chr_W0 = (const float*)d_in[6];
    const float* chr_W1 = (const float*)d_in[7];
    const float* chr_W2 = (const float*)d_in[8];
    const float* slv_W0 = (const float*)d_in[9];
    const float* slv_W1 = (const float*)d_in[10];
    const float* slv_W2 = (const float*)d_in[11];
    const float* cfc_W = (const float*)d_in[12];
    const float* cfc_b = (const float*)d_in[13];
    const float* sfc_W = (const float*)d_in[14];
    const float* sfc_b = (const float*)d_in[15];
    const float* fc1_W = (const float*)d_in[16];
    const float* fc1_b = (const float*)d_in[17];
    const float* fc2_W = (const float*)d_in[18];
    const float* fc2_b = (const float*)d_in[19];
    float* out = (float*)d_out;

    char* w = (char*)d_ws;
    auto carve = [&](size_t bytes) {
        void* p = (void*)w;
        w += (bytes + 255) & ~(size_t)255;
        return p;
    };
    int* off_chr = (int*)carve((N_CHR + 1) * sizeof(int));
    int* csr_chr = (int*)carve((size_t)E_CHR * sizeof(int));
    int* off_slv = (int*)carve((N_SLV + 1) * sizeof(int));
    int* csr_slv = (int*)carve((size_t)E_SLV * sizeof(int));
    int* cnt     = (int*)carve((size_t)(N_CHR + N_SLV) * sizeof(int));
    int* cursor  = (int*)carve((size_t)(N_CHR + N_SLV) * sizeof(int));
    int* bsum    = (int*)carve(2 * SCAN_BLOCKS * sizeof(int));
    int* start_chr = (int*)carve((BATCH_B + 1) * sizeof(int));
    int* start_slv = (int*)carve((BATCH_B + 1) * sizeof(int));
    u16* cW0t = (u16*)carve((size_t)ENSN * DIM * FEAT * sizeof(u16));
    u16* cW1t = (u16*)carve((size_t)ENSN * DIM * DIM * sizeof(u16));
    u16* cW2t = (u16*)carve((size_t)ENSN * HALF * DIM * sizeof(u16));
    u16* sW0t = (u16*)carve((size_t)ENSN * DIM * FEAT * sizeof(u16));
    u16* sW1t = (u16*)carve((size_t)ENSN * DIM * DIM * sizeof(u16));
    u16* sW2t = (u16*)carve((size_t)ENSN * HALF * DIM * sizeof(u16));
    u16* xb_chr = (u16*)carve((size_t)N_CHR * FEAT * sizeof(u16));
    u16* xb_slv = (u16*)carve((size_t)N_SLV * FEAT * sizeof(u16));
    u16* aggX = (u16*)carve((size_t)N_CHR * FEAT * sizeof(u16));
    u16* bufP = (u16*)carve((size_t)ENSN * N_CHR * DIM * sizeof(u16));
    u16* bufQ = (u16*)carve((size_t)ENSN * N_CHR * DIM * sizeof(u16));
    float* rep = (float*)carve((size_t)BATCH_B * 2 * ENSN * HALF * sizeof(float));
    float* hg  = (float*)carve((size_t)BATCH_B * 2 * ENSN * DIM * sizeof(float));

    // ---- converts ----
    xconv_k<<<512, 256, 0, stream>>>(chr_x, slv_x, xb_chr, xb_slv);
    wconv_k<<<dim3((FEAT * DIM + 255) / 256, ENSN, 2), 256, 0, stream>>>(chr_W0, slv_W0, cW0t, sW0t, FEAT, DIM);
    wconv_k<<<dim3((DIM * DIM + 255) / 256, ENSN, 2), 256, 0, stream>>>(chr_W1, slv_W1, cW1t, sW1t, DIM, DIM);
    wconv_k<<<dim3((DIM * HALF + 255) / 256, ENSN, 2), 256, 0, stream>>>(chr_W2, slv_W2, cW2t, sW2t, DIM, HALF);

    // ---- CSR build (both graphs) ----
    hipMemsetAsync(cnt, 0, (N_CHR + N_SLV) * sizeof(int), stream);
    hist_both_k<<<512, 256, 0, stream>>>(chr_ei + E_CHR, slv_ei + E_SLV, cnt);
    scanA_k<<<2 * SCAN_BLOCKS, 256, 0, stream>>>(cnt, bsum);
    scanB_k<<<1, SCAN_BLOCKS, 0, stream>>>(bsum, off_chr, off_slv);
    scanC_k<<<2 * SCAN_BLOCKS, 256, 0, stream>>>(cnt, bsum, off_chr, off_slv, cursor);
    fill_both_k<<<512, 256, 0, stream>>>(chr_ei, slv_ei, cursor, csr_chr, csr_slv);
    bounds_both_k<<<1, 640, 0, stream>>>(chr_batch, slv_batch, start_chr, start_slv);

    // ---- chr branch ----
    agg1_k<<<(N_CHR + 1) / 2, 64, 0, stream>>>(xb_chr, off_chr, csr_chr, aggX, N_CHR);
    gemm_mfma_k<FEAT, DIM, true><<<dim3((N_CHR + 255) / 256, ENSN), 256, 0, stream>>>(
        aggX, 0, cW0t, bufP, N_CHR);
    aggb128_k<false><<<dim3((N_CHR + 1) / 2, ENSN), 64, 0, stream>>>(bufP, off_chr, csr_chr, bufQ, N_CHR);
    gemm_mfma_k<DIM, DIM, true><<<dim3((N_CHR + 255) / 256, ENSN), 256, 0, stream>>>(
        bufQ, (size_t)N_CHR * DIM, cW1t, bufP, N_CHR);
    gemm_mfma_k<DIM, HALF, false><<<dim3((N_CHR + 255) / 256, ENSN), 256, 0, stream>>>(
        bufP, (size_t)N_CHR * DIM, cW2t, bufQ, N_CHR);
    aggb64_k<true><<<dim3((N_CHR + 3) / 4, ENSN), 64, 0, stream>>>(bufQ, off_chr, csr_chr, bufP, N_CHR);
    pool_b_k<<<dim3(BATCH_B, ENSN), 256, 0, stream>>>(bufP, start_chr, rep, N_CHR, 0);

    // ---- slv branch ----
    agg1_k<<<(N_SLV + 1) / 2, 64, 0, stream>>>(xb_slv, off_slv, csr_slv, aggX, N_SLV);
    gemm_mfma_k<FEAT, DIM, true><<<dim3((N_SLV + 255) / 256, ENSN), 256, 0, stream>>>(
        aggX, 0, sW0t, bufP, N_SLV);
    aggb128_k<false><<<dim3((N_SLV + 1) / 2, ENSN), 64, 0, stream>>>(bufP, off_slv, csr_slv, bufQ, N_SLV);
    gemm_mfma_k<DIM, DIM, true><<<dim3((N_SLV + 255) / 256, ENSN), 256, 0, stream>>>(
        bufQ, (size_t)N_SLV * DIM, sW1t, bufP, N_SLV);
    gemm_mfma_k<DIM, HALF, false><<<dim3((N_SLV + 255) / 256, ENSN), 256, 0, stream>>>(
        bufP, (size_t)N_SLV * DIM, sW2t, bufQ, N_SLV);
    aggb64_k<true><<<dim3((N_SLV + 3) / 4, ENSN), 64, 0, stream>>>(bufQ, off_slv, csr_slv, bufP, N_SLV);
    pool_b_k<<<dim3(BATCH_B, ENSN), 256, 0, stream>>>(bufP, start_slv, rep, N_SLV, ENSN * HALF);

    // ---- heads + final MLP ----
    head_k<<<dim3(BATCH_B, 2 * ENSN), DIM, 0, stream>>>(rep, cfc_W, cfc_b, sfc_W, sfc_b, hg);
    final_k<<<BATCH_B, DIM, 0, stream>>>(hg, fc1_W, fc1_b, fc2_W, fc2_b, out);
}